// Round 6
// baseline (313.037 us; speedup 1.0000x reference)
//
#include <hip/hip_runtime.h>
#include <hip/hip_fp16.h>

#define N_NODESC 50000
#define N_EDGESC 800000
#define N_GROUPS 3125      // 16 nodes per group
#define GSLOTS 512         // mean 256, sd 16 -> +16 sigma, overflow prob ~0

typedef short bf16x8 __attribute__((ext_vector_type(8)));   // 8 bf16 = 4 VGPRs
typedef float f32x4  __attribute__((ext_vector_type(4)));

__device__ inline unsigned short f2bf(float f) {            // RNE fp32->bf16
    unsigned u = __float_as_uint(f);
    unsigned r = u + 0x7FFFu + ((u >> 16) & 1u);
    return (unsigned short)(r >> 16);
}
__device__ inline float bf2f(unsigned short h) {
    return __uint_as_float(((unsigned)h) << 16);
}

// ---------------- K0: zero-init gcnt + z (ws is poisoned 0xAA every call) ---
__global__ void k0_init(int* __restrict__ gcnt, float* __restrict__ z) {
    int i = blockIdx.x * 256 + threadIdx.x;
    if (i < N_GROUPS) gcnt[i] = 0;
    if (i < 256) z[i] = 0.0f;
}

// ---------------- KH: x -> fp16 copy (halves k2's gather traffic) -----------
__global__ void k_half(const float* __restrict__ x, __half* __restrict__ xh) {
    int i = (blockIdx.x * 256 + threadIdx.x) * 4;   // 3125*256*4 == 3,200,000
    float4 f = *(const float4*)(x + i);
    __half2 h01 = __floats2half2_rn(f.x, f.y);
    __half2 h23 = __floats2half2_rn(f.z, f.w);
    uint2 u;
    u.x = *(unsigned*)&h01;
    u.y = *(unsigned*)&h23;
    *(uint2*)(xh + i) = u;
}

// ---------------- K1: packed group-bucket build -----------------------------
// Entry = src(16b) | localdst(4b)<<16, appended to the dst-group's 2KB row.
// One atomic per edge; rows are dense (~85% of touched lines used) so the
// scattered stores L2-merge into full lines. 8 dst-range groups ride the
// round-robin block->XCD mapping (locality heuristic only).
#define K1_BLOCKS 2048
#define K1_EPB (N_EDGESC / (K1_BLOCKS / 8))   // 3125 edges per block
__global__ void k1_bucket(const int* __restrict__ ei, int* __restrict__ gcnt,
                          int* __restrict__ gbucket) {
    int g   = blockIdx.x & 7;
    int idx = blockIdx.x >> 3;
    int lo = g * (N_NODESC / 8), hi = lo + (N_NODESC / 8);
    int e0 = idx * K1_EPB;
    for (int i = threadIdx.x; i < K1_EPB; i += 256) {
        int e = e0 + i;
        int dst = ei[N_EDGESC + e];
        if (dst >= lo && dst < hi) {
            int src = ei[e];
            int grp = dst >> 4;
            int slot = atomicAdd(&gcnt[grp], 1);
            if (slot < GSLOTS) gbucket[grp * GSLOTS + slot] = src | ((dst & 15) << 16);
        }
    }
}

// ---------------- K2: layer-1 mean aggregation over packed buckets ----------
// 1 block per 16-node group. LDS counting-sort entries by local dst, then
// wave w owns nodes 4w..4w+3 (contiguous sorted segments). Gathers are fp16
// half2 (lane = channel pair, 2 entries per wave-iter); accumulate fp32 in
// registers; deg = segment length (recounted here, no global deg array).
__global__ void k2_agg(const __half* __restrict__ xh, const int* __restrict__ gcnt,
                       const int* __restrict__ gbucket, float* __restrict__ agg) {
    __shared__ int eArr[GSLOTS];
    __shared__ unsigned short sorted[GSLOTS];
    __shared__ int hist[16], offs[17], cursor[16];

    int g = blockIdx.x;
    int tid = threadIdx.x;
    int cnt = min(gcnt[g], GSLOTS);

    if (tid < 16) hist[tid] = 0;
    __syncthreads();
    for (int i = tid; i < cnt; i += 256) {
        int p = gbucket[g * GSLOTS + i];
        eArr[i] = p;
        atomicAdd(&hist[(p >> 16) & 15], 1);
    }
    __syncthreads();
    if (tid == 0) {
        int r = 0;
        #pragma unroll
        for (int j = 0; j < 16; j++) { offs[j] = r; r += hist[j]; }
        offs[16] = r;
    }
    __syncthreads();
    if (tid < 16) cursor[tid] = offs[tid];
    __syncthreads();
    for (int i = tid; i < cnt; i += 256) {
        int p = eArr[i];
        int pos = atomicAdd(&cursor[(p >> 16) & 15], 1);
        sorted[pos] = (unsigned short)(p & 0xFFFF);
    }
    __syncthreads();

    int lane = tid & 63;
    int w = tid >> 6;
    int hsel = lane >> 5;      // entry parity
    int c2 = lane & 31;        // channel pair: ch {2c2, 2c2+1}

    #pragma unroll
    for (int ni = 0; ni < 4; ni++) {
        int n = w * 4 + ni;
        int b = offs[n], e = offs[n + 1];
        float ax = 0.f, ay = 0.f;
        for (int j = b + hsel; j < e; j += 2) {
            int src = sorted[j];
            __half2 h = *(const __half2*)(xh + src * 64 + c2 * 2);
            float2 f = __half22float2(h);
            ax += f.x; ay += f.y;
        }
        ax += __shfl_xor(ax, 32);
        ay += __shfl_xor(ay, 32);
        if (lane < 32) {
            int node = g * 16 + n;
            float inv = 1.0f / (float)max(e - b, 1);
            *(float2*)(agg + node * 64 + c2 * 2) = make_float2(ax * inv, ay * inv);
        }
    }
}

// ---------------- K3: layer-1 via 3-term bf16 MFMA + fused (s,t) epilogue ---
// (unchanged from R4: absmax 0.0, off the critical profile)
#define K3S 144   // LDS row stride in bf16 elems (128 + 16 pad)

__launch_bounds__(256, 3)
__global__ void k3_mm_mfma(const float* __restrict__ x, const float* __restrict__ agg,
                           const float* __restrict__ W1l, const float* __restrict__ b1l,
                           const float* __restrict__ W1r,
                           const float* __restrict__ W2l, const float* __restrict__ W2r,
                           float* __restrict__ s_out, float* __restrict__ t_out) {
    __shared__ __align__(16) short sAhi[64 * K3S];   // 18432 B
    __shared__ __align__(16) short sAlo[64 * K3S];   // 18432 B
    __shared__ float sS[64], sT[64];

    int tid = threadIdx.x;
    int lane = tid & 63;
    int wave = tid >> 6;
    int col = lane & 15;
    int quad = lane >> 4;
    int node0 = blockIdx.x * 64;

    if (tid < 64) { sS[tid] = 0.f; sT[tid] = 0.f; }

    int o_base = wave * 32;
    bf16x8 bhi[2][4], blo[2][4];
    float bias_r[2], w2l_r[2], w2r_r[2];
    #pragma unroll
    for (int oc = 0; oc < 2; oc++) {
        int o = o_base + oc * 16 + col;
        bias_r[oc] = b1l[o]; w2l_r[oc] = W2l[o]; w2r_r[oc] = W2r[o];
        #pragma unroll
        for (int ks = 0; ks < 4; ks++) {
            int k0 = ks * 32 + quad * 8;
            const float* wrow = (k0 < 64) ? (W1r + o * 64 + k0)
                                          : (W1l + o * 64 + (k0 - 64));
            #pragma unroll
            for (int j = 0; j < 8; j++) {
                float w = wrow[j];
                unsigned short h = f2bf(w);
                bhi[oc][ks][j] = (short)h;
                blo[oc][ks][j] = (short)f2bf(w - bf2f(h));
            }
        }
    }

    #pragma unroll
    for (int i = 0; i < 4; i++) {
        int c = tid + 256 * i;            // 1024 chunks of 8 elems
        int n = c >> 4, kc = c & 15;
        int node = node0 + n;
        float v[8];
        if (node < N_NODESC) {
            const float* src = (kc < 8) ? (x + node * 64 + kc * 8)
                                        : (agg + node * 64 + (kc - 8) * 8);
            float4 v0 = *(const float4*)src;
            float4 v1 = *(const float4*)(src + 4);
            v[0] = v0.x; v[1] = v0.y; v[2] = v0.z; v[3] = v0.w;
            v[4] = v1.x; v[5] = v1.y; v[6] = v1.z; v[7] = v1.w;
        } else {
            #pragma unroll
            for (int j = 0; j < 8; j++) v[j] = 0.f;
        }
        bf16x8 hv, lv;
        #pragma unroll
        for (int j = 0; j < 8; j++) {
            unsigned short h = f2bf(v[j]);
            hv[j] = (short)h;
            lv[j] = (short)f2bf(v[j] - bf2f(h));
        }
        *(bf16x8*)&sAhi[n * K3S + kc * 8] = hv;
        *(bf16x8*)&sAlo[n * K3S + kc * 8] = lv;
    }
    __syncthreads();

    f32x4 acc[4][2];
    #pragma unroll
    for (int nt = 0; nt < 4; nt++)
        #pragma unroll
        for (int oc = 0; oc < 2; oc++) acc[nt][oc] = (f32x4)0.f;

    #pragma unroll
    for (int ks = 0; ks < 4; ks++) {
        #pragma unroll
        for (int nt = 0; nt < 4; nt++) {
            int off = (nt * 16 + col) * K3S + ks * 32 + quad * 8;
            bf16x8 ah = *(const bf16x8*)&sAhi[off];
            bf16x8 al = *(const bf16x8*)&sAlo[off];
            #pragma unroll
            for (int oc = 0; oc < 2; oc++) {
                acc[nt][oc] = __builtin_amdgcn_mfma_f32_16x16x32_bf16(ah, bhi[oc][ks], acc[nt][oc], 0, 0, 0);
                acc[nt][oc] = __builtin_amdgcn_mfma_f32_16x16x32_bf16(al, bhi[oc][ks], acc[nt][oc], 0, 0, 0);
                acc[nt][oc] = __builtin_amdgcn_mfma_f32_16x16x32_bf16(ah, blo[oc][ks], acc[nt][oc], 0, 0, 0);
            }
        }
    }

    #pragma unroll
    for (int nt = 0; nt < 4; nt++) {
        float sp[4] = {0.f, 0.f, 0.f, 0.f};
        float tp[4] = {0.f, 0.f, 0.f, 0.f};
        #pragma unroll
        for (int oc = 0; oc < 2; oc++)
            #pragma unroll
            for (int reg = 0; reg < 4; reg++) {
                float h = fmaxf(acc[nt][oc][reg] + bias_r[oc], 0.f);
                sp[reg] += h * w2l_r[oc];
                tp[reg] += h * w2r_r[oc];
            }
        #pragma unroll
        for (int reg = 0; reg < 4; reg++) {
            #pragma unroll
            for (int m = 1; m <= 8; m <<= 1) {
                sp[reg] += __shfl_xor(sp[reg], m);
                tp[reg] += __shfl_xor(tp[reg], m);
            }
        }
        if (col == 0) {
            int nn = nt * 16 + quad * 4;
            #pragma unroll
            for (int reg = 0; reg < 4; reg++) {
                atomicAdd(&sS[nn + reg], sp[reg]);
                atomicAdd(&sT[nn + reg], tp[reg]);
            }
        }
    }
    __syncthreads();
    if (tid < 64) {
        int node = node0 + tid;
        if (node < N_NODESC) { s_out[node] = sS[tid]; t_out[node] = sT[tid]; }
    }
}

// ---------------- K4: layer-2 scalar aggregation + relu -> v ----------------
// 1 wave per group; LDS float accumulators per local node (16 hot addrs,
// order-nondeterministic adds -- absmax budget covers it).
__global__ void k4_layer2(const float* __restrict__ s, const float* __restrict__ t,
                          const int* __restrict__ gcnt, const int* __restrict__ gbucket,
                          const float* __restrict__ b2l, float* __restrict__ v) {
    __shared__ float accS[16];
    __shared__ int cntS[16];
    int g = blockIdx.x;
    int lane = threadIdx.x;   // 64 threads
    if (lane < 16) { accS[lane] = 0.f; cntS[lane] = 0; }
    __syncthreads();
    int cnt = min(gcnt[g], GSLOTS);
    for (int i = lane; i < cnt; i += 64) {
        int p = gbucket[g * GSLOTS + i];
        atomicAdd(&accS[(p >> 16) & 15], s[p & 0xFFFF]);
        atomicAdd(&cntS[(p >> 16) & 15], 1);
    }
    __syncthreads();
    if (lane < 16) {
        int node = g * 16 + lane;
        float h = accS[lane] / (float)max(cntS[lane], 1) + b2l[0] + t[node];
        v[node] = fmaxf(h, 0.f);
    }
}

// ---------------- K5: z_partial = fc1_W @ v (bias deferred to K6) -----------
__global__ void k5_fc1(const float* __restrict__ fc1W, const float* __restrict__ v,
                       float* __restrict__ z) {
    int row = blockIdx.x >> 2;
    int part = blockIdx.x & 3;
    const float4* W4 = (const float4*)(fc1W + row * 50000 + part * 12500);
    const float4* v4 = (const float4*)(v + part * 12500);
    float sum = 0.f;
    for (int i = threadIdx.x; i < 3125; i += 256) {
        float4 w = W4[i], a = v4[i];
        sum += w.x * a.x + w.y * a.y + w.z * a.z + w.w * a.w;
    }
    #pragma unroll
    for (int m = 1; m < 64; m <<= 1) sum += __shfl_xor(sum, m);
    __shared__ float red[4];
    if ((threadIdx.x & 63) == 0) red[threadIdx.x >> 6] = sum;
    __syncthreads();
    if (threadIdx.x == 0) atomicAdd(&z[row], red[0] + red[1] + red[2] + red[3]);
}

// ---------------- K6: pred = fc2_W @ (z + fc1_b) + fc2_b --------------------
__global__ void k6_head(const float* __restrict__ z, const float* __restrict__ fc1b,
                        const float* __restrict__ fc2W, const float* __restrict__ fc2b,
                        float* __restrict__ out) {
    int t = threadIdx.x;  // 256 threads
    float val = (z[t] + fc1b[t]) * fc2W[t];
    #pragma unroll
    for (int m = 1; m < 64; m <<= 1) val += __shfl_xor(val, m);
    __shared__ float red[4];
    if ((t & 63) == 0) red[t >> 6] = val;
    __syncthreads();
    if (t == 0) out[0] = red[0] + red[1] + red[2] + red[3] + fc2b[0];
}

extern "C" void kernel_launch(void* const* d_in, const int* in_sizes, int n_in,
                              void* d_out, int out_size, void* d_ws, size_t ws_size,
                              hipStream_t stream) {
    const float* x    = (const float*)d_in[0];
    const int*   ei   = (const int*)d_in[1];   // jax x64 disabled -> int32
    const float* W1l  = (const float*)d_in[2];
    const float* b1l  = (const float*)d_in[3];
    const float* W1r  = (const float*)d_in[4];
    const float* W2l  = (const float*)d_in[5];
    const float* b2l  = (const float*)d_in[6];
    const float* W2r  = (const float*)d_in[7];
    const float* fc1W = (const float*)d_in[8];
    const float* fc1b = (const float*)d_in[9];
    const float* fc2W = (const float*)d_in[10];
    const float* fc2b = (const float*)d_in[11];
    float* out = (float*)d_out;

    // workspace layout (bytes)
    char*   ws      = (char*)d_ws;
    int*    gcnt    = (int*)   (ws + 0);           //    12,500 B
    float*  z       = (float*) (ws + 12800);       //     1,024 B
    __half* xh      = (__half*)(ws + 14336);       // 6,400,000 B
    int*    gbucket = (int*)   (ws + 6414336);     // 6,400,000 B
    float*  agg     = (float*) (ws + 12814336);    // 12,800,000 B
    float*  s       = (float*) (ws + 25614336);    //   200,000 B
    float*  t       = (float*) (ws + 25814336);    //   200,000 B
    float*  v       = (float*) (ws + 26014336);    //   200,000 B  (end 26,214,336)

    k0_init   <<<16,        256, 0, stream>>>(gcnt, z);
    k_half    <<<3125,      256, 0, stream>>>(x, xh);
    k1_bucket <<<K1_BLOCKS, 256, 0, stream>>>(ei, gcnt, gbucket);
    k2_agg    <<<N_GROUPS,  256, 0, stream>>>(xh, gcnt, gbucket, agg);
    k3_mm_mfma<<<782,       256, 0, stream>>>(x, agg, W1l, b1l, W1r, W2l, W2r, s, t);
    k4_layer2 <<<N_GROUPS,   64, 0, stream>>>(s, t, gcnt, gbucket, b2l, v);
    k5_fc1    <<<1024,      256, 0, stream>>>(fc1W, v, z);
    k6_head   <<<1,         256, 0, stream>>>(z, fc1b, fc2W, fc2b, out);
}

// Round 7
// 245.510 us; speedup vs baseline: 1.2750x; 1.2750x over previous
//
#include <hip/hip_runtime.h>
#include <hip/hip_fp16.h>

#define N_NODESC 50000
#define N_EDGESC 800000
#define N_GROUPS 3125      // 16 nodes per group
#define GSLOTS 512         // 4 replicas x 128 slots; mean 64/replica, P(>128)~2e-11

typedef short bf16x8 __attribute__((ext_vector_type(8)));   // 8 bf16 = 4 VGPRs
typedef float f32x4  __attribute__((ext_vector_type(4)));

__device__ inline unsigned short f2bf(float f) {            // RNE fp32->bf16
    unsigned u = __float_as_uint(f);
    unsigned r = u + 0x7FFFu + ((u >> 16) & 1u);
    return (unsigned short)(r >> 16);
}
__device__ inline float bf2f(unsigned short h) {
    return __uint_as_float(((unsigned)h) << 16);
}

// ---------------- K0: fp16 convert + zero counters/z/done (fused) -----------
__global__ void k0_half_init(const float* __restrict__ x, __half* __restrict__ xh,
                             int* __restrict__ gcnt4, float* __restrict__ z,
                             int* __restrict__ done) {
    int gi = blockIdx.x * 256 + threadIdx.x;
    int i = gi * 4;                               // 3125*256*4 == 3,200,000
    float4 f = *(const float4*)(x + i);
    __half2 h01 = __floats2half2_rn(f.x, f.y);
    __half2 h23 = __floats2half2_rn(f.z, f.w);
    uint2 u;
    u.x = *(unsigned*)&h01;
    u.y = *(unsigned*)&h23;
    *(uint2*)(xh + i) = u;
    if (gi < N_GROUPS * 64) gcnt4[gi] = 0;        // 200,000 ints, grid covers 800k
    if (blockIdx.x == 3124) {
        z[threadIdx.x] = 0.f;
        if (threadIdx.x == 0) *done = 0;
    }
}

// ---------------- K1: packed group-bucket build, contention-spread ----------
// Entry = src(16b) | localdst(4b)<<16. Counter for (grp, rep) sits on its OWN
// 64B line (R6 lesson: 16 counters/line x 256 ops = 4096 atomics/line was the
// 130us regression; now 64 ops/line). rep=(blockIdx>>3)&3 owns a 128-slot
// quarter of the 2KB group row. 8 dst-range groups ride the round-robin
// block->XCD mapping (locality heuristic only; correctness placement-free).
#define K1_BLOCKS 2048
#define K1_EPB (N_EDGESC / (K1_BLOCKS / 8))   // 3125 edges per block
__global__ void k1_bucket(const int* __restrict__ ei, int* __restrict__ gcnt4,
                          int* __restrict__ gbucket) {
    int g   = blockIdx.x & 7;
    int idx = blockIdx.x >> 3;
    int rep = idx & 3;
    int lo = g * (N_NODESC / 8), hi = lo + (N_NODESC / 8);
    int e0 = idx * K1_EPB;
    for (int i = threadIdx.x; i < K1_EPB; i += 256) {
        int e = e0 + i;
        int dst = ei[N_EDGESC + e];
        if (dst >= lo && dst < hi) {
            int src = ei[e];
            int grp = dst >> 4;
            int slot = atomicAdd(&gcnt4[grp * 64 + rep * 16], 1);
            if (slot < 128)
                gbucket[grp * GSLOTS + rep * 128 + slot] = src | ((dst & 15) << 16);
        }
    }
}

// ---------------- K2: layer-1 mean aggregation over packed buckets ----------
// 1 block per 16-node group. Concatenate the 4 sub-rows, LDS counting-sort by
// local dst, then wave w owns nodes 4w..4w+3 (contiguous segments). fp16
// half2 gathers (lane = channel pair, 2 entries in flight); fp32 accumulate.
__global__ void k2_agg(const __half* __restrict__ xh, const int* __restrict__ gcnt4,
                       const int* __restrict__ gbucket, float* __restrict__ agg) {
    __shared__ int eArr[GSLOTS];
    __shared__ unsigned short sorted[GSLOTS];
    __shared__ int hist[16], offs[17], cursor[16];

    int g = blockIdx.x;
    int tid = threadIdx.x;

    int c[4], off[5];
    off[0] = 0;
    #pragma unroll
    for (int r = 0; r < 4; r++) {
        c[r] = min(gcnt4[g * 64 + r * 16], 128);
        off[r + 1] = off[r] + c[r];
    }
    int cnt = off[4];

    if (tid < 16) hist[tid] = 0;
    __syncthreads();
    #pragma unroll
    for (int r = 0; r < 4; r++) {
        for (int i = tid; i < c[r]; i += 256) {
            int p = gbucket[g * GSLOTS + r * 128 + i];
            eArr[off[r] + i] = p;
            atomicAdd(&hist[(p >> 16) & 15], 1);
        }
    }
    __syncthreads();
    if (tid == 0) {
        int run = 0;
        #pragma unroll
        for (int j = 0; j < 16; j++) { offs[j] = run; run += hist[j]; }
        offs[16] = run;
    }
    __syncthreads();
    if (tid < 16) cursor[tid] = offs[tid];
    __syncthreads();
    for (int i = tid; i < cnt; i += 256) {
        int p = eArr[i];
        int pos = atomicAdd(&cursor[(p >> 16) & 15], 1);
        sorted[pos] = (unsigned short)(p & 0xFFFF);
    }
    __syncthreads();

    int lane = tid & 63;
    int w = tid >> 6;
    int hsel = lane >> 5;      // entry parity
    int c2 = lane & 31;        // channel pair: ch {2c2, 2c2+1}

    #pragma unroll
    for (int ni = 0; ni < 4; ni++) {
        int n = w * 4 + ni;
        int b = offs[n], e = offs[n + 1];
        float ax = 0.f, ay = 0.f;
        for (int j = b + hsel; j < e; j += 2) {
            int src = sorted[j];
            __half2 h = *(const __half2*)(xh + src * 64 + c2 * 2);
            float2 f = __half22float2(h);
            ax += f.x; ay += f.y;
        }
        ax += __shfl_xor(ax, 32);
        ay += __shfl_xor(ay, 32);
        if (lane < 32) {
            int node = g * 16 + n;
            float inv = 1.0f / (float)max(e - b, 1);
            *(float2*)(agg + node * 64 + c2 * 2) = make_float2(ax * inv, ay * inv);
        }
    }
}

// ---------------- K3: layer-1 via 3-term bf16 MFMA + fused (s,t) epilogue ---
// (unchanged: absmax 0.0, off the critical profile)
#define K3S 144   // LDS row stride in bf16 elems (128 + 16 pad)

__launch_bounds__(256, 3)
__global__ void k3_mm_mfma(const float* __restrict__ x, const float* __restrict__ agg,
                           const float* __restrict__ W1l, const float* __restrict__ b1l,
                           const float* __restrict__ W1r,
                           const float* __restrict__ W2l, const float* __restrict__ W2r,
                           float* __restrict__ s_out, float* __restrict__ t_out) {
    __shared__ __align__(16) short sAhi[64 * K3S];   // 18432 B
    __shared__ __align__(16) short sAlo[64 * K3S];   // 18432 B
    __shared__ float sS[64], sT[64];

    int tid = threadIdx.x;
    int lane = tid & 63;
    int wave = tid >> 6;
    int col = lane & 15;
    int quad = lane >> 4;
    int node0 = blockIdx.x * 64;

    if (tid < 64) { sS[tid] = 0.f; sT[tid] = 0.f; }

    int o_base = wave * 32;
    bf16x8 bhi[2][4], blo[2][4];
    float bias_r[2], w2l_r[2], w2r_r[2];
    #pragma unroll
    for (int oc = 0; oc < 2; oc++) {
        int o = o_base + oc * 16 + col;
        bias_r[oc] = b1l[o]; w2l_r[oc] = W2l[o]; w2r_r[oc] = W2r[o];
        #pragma unroll
        for (int ks = 0; ks < 4; ks++) {
            int k0 = ks * 32 + quad * 8;
            const float* wrow = (k0 < 64) ? (W1r + o * 64 + k0)
                                          : (W1l + o * 64 + (k0 - 64));
            #pragma unroll
            for (int j = 0; j < 8; j++) {
                float w = wrow[j];
                unsigned short h = f2bf(w);
                bhi[oc][ks][j] = (short)h;
                blo[oc][ks][j] = (short)f2bf(w - bf2f(h));
            }
        }
    }

    #pragma unroll
    for (int i = 0; i < 4; i++) {
        int cidx = tid + 256 * i;         // 1024 chunks of 8 elems
        int n = cidx >> 4, kc = cidx & 15;
        int node = node0 + n;
        float v[8];
        if (node < N_NODESC) {
            const float* src = (kc < 8) ? (x + node * 64 + kc * 8)
                                        : (agg + node * 64 + (kc - 8) * 8);
            float4 v0 = *(const float4*)src;
            float4 v1 = *(const float4*)(src + 4);
            v[0] = v0.x; v[1] = v0.y; v[2] = v0.z; v[3] = v0.w;
            v[4] = v1.x; v[5] = v1.y; v[6] = v1.z; v[7] = v1.w;
        } else {
            #pragma unroll
            for (int j = 0; j < 8; j++) v[j] = 0.f;
        }
        bf16x8 hv, lv;
        #pragma unroll
        for (int j = 0; j < 8; j++) {
            unsigned short h = f2bf(v[j]);
            hv[j] = (short)h;
            lv[j] = (short)f2bf(v[j] - bf2f(h));
        }
        *(bf16x8*)&sAhi[n * K3S + kc * 8] = hv;
        *(bf16x8*)&sAlo[n * K3S + kc * 8] = lv;
    }
    __syncthreads();

    f32x4 acc[4][2];
    #pragma unroll
    for (int nt = 0; nt < 4; nt++)
        #pragma unroll
        for (int oc = 0; oc < 2; oc++) acc[nt][oc] = (f32x4)0.f;

    #pragma unroll
    for (int ks = 0; ks < 4; ks++) {
        #pragma unroll
        for (int nt = 0; nt < 4; nt++) {
            int offA = (nt * 16 + col) * K3S + ks * 32 + quad * 8;
            bf16x8 ah = *(const bf16x8*)&sAhi[offA];
            bf16x8 al = *(const bf16x8*)&sAlo[offA];
            #pragma unroll
            for (int oc = 0; oc < 2; oc++) {
                acc[nt][oc] = __builtin_amdgcn_mfma_f32_16x16x32_bf16(ah, bhi[oc][ks], acc[nt][oc], 0, 0, 0);
                acc[nt][oc] = __builtin_amdgcn_mfma_f32_16x16x32_bf16(al, bhi[oc][ks], acc[nt][oc], 0, 0, 0);
                acc[nt][oc] = __builtin_amdgcn_mfma_f32_16x16x32_bf16(ah, blo[oc][ks], acc[nt][oc], 0, 0, 0);
            }
        }
    }

    #pragma unroll
    for (int nt = 0; nt < 4; nt++) {
        float sp[4] = {0.f, 0.f, 0.f, 0.f};
        float tp[4] = {0.f, 0.f, 0.f, 0.f};
        #pragma unroll
        for (int oc = 0; oc < 2; oc++)
            #pragma unroll
            for (int reg = 0; reg < 4; reg++) {
                float h = fmaxf(acc[nt][oc][reg] + bias_r[oc], 0.f);
                sp[reg] += h * w2l_r[oc];
                tp[reg] += h * w2r_r[oc];
            }
        #pragma unroll
        for (int reg = 0; reg < 4; reg++) {
            #pragma unroll
            for (int m = 1; m <= 8; m <<= 1) {
                sp[reg] += __shfl_xor(sp[reg], m);
                tp[reg] += __shfl_xor(tp[reg], m);
            }
        }
        if (col == 0) {
            int nn = nt * 16 + quad * 4;
            #pragma unroll
            for (int reg = 0; reg < 4; reg++) {
                atomicAdd(&sS[nn + reg], sp[reg]);
                atomicAdd(&sT[nn + reg], tp[reg]);
            }
        }
    }
    __syncthreads();
    if (tid < 64) {
        int node = node0 + tid;
        if (node < N_NODESC) { s_out[node] = sS[tid]; t_out[node] = sT[tid]; }
    }
}

// ---------------- K4: layer-2 scalar aggregation + relu -> v ----------------
__global__ void k4_layer2(const float* __restrict__ s, const float* __restrict__ t,
                          const int* __restrict__ gcnt4, const int* __restrict__ gbucket,
                          const float* __restrict__ b2l, float* __restrict__ v) {
    __shared__ float accS[16];
    __shared__ int cntS[16];
    int g = blockIdx.x;
    int lane = threadIdx.x;   // 64 threads
    if (lane < 16) { accS[lane] = 0.f; cntS[lane] = 0; }
    __syncthreads();
    #pragma unroll
    for (int r = 0; r < 4; r++) {
        int cr = min(gcnt4[g * 64 + r * 16], 128);
        for (int i = lane; i < cr; i += 64) {
            int p = gbucket[g * GSLOTS + r * 128 + i];
            atomicAdd(&accS[(p >> 16) & 15], s[p & 0xFFFF]);
            atomicAdd(&cntS[(p >> 16) & 15], 1);
        }
    }
    __syncthreads();
    if (lane < 16) {
        int node = g * 16 + lane;
        float h = accS[lane] / (float)max(cntS[lane], 1) + b2l[0] + t[node];
        v[node] = fmaxf(h, 0.f);
    }
}

// ---------------- K5: z = fc1_W @ v, then last block does the k6 head -------
// 1024 blocks; each adds its partial to z[row] (device-scope atomic), fences,
// takes a ticket; the single block seeing ticket==1023 re-reads z with
// agent-scope atomic loads (coherent across XCDs) and computes the scalar out.
__global__ void k5_fc1_head(const float* __restrict__ fc1W, const float* __restrict__ v,
                            float* __restrict__ z, int* __restrict__ done,
                            const float* __restrict__ fc1b, const float* __restrict__ fc2W,
                            const float* __restrict__ fc2b, float* __restrict__ out) {
    int row = blockIdx.x >> 2;
    int part = blockIdx.x & 3;
    const float4* W4 = (const float4*)(fc1W + row * 50000 + part * 12500);
    const float4* v4 = (const float4*)(v + part * 12500);
    float sum = 0.f;
    for (int i = threadIdx.x; i < 3125; i += 256) {
        float4 w = W4[i], a = v4[i];
        sum += w.x * a.x + w.y * a.y + w.z * a.z + w.w * a.w;
    }
    #pragma unroll
    for (int m = 1; m < 64; m <<= 1) sum += __shfl_xor(sum, m);
    __shared__ float red[4];
    __shared__ int ticket;
    if ((threadIdx.x & 63) == 0) red[threadIdx.x >> 6] = sum;
    __syncthreads();
    if (threadIdx.x == 0) {
        atomicAdd(&z[row], red[0] + red[1] + red[2] + red[3]);
        __threadfence();                       // z-add visible before ticket
        ticket = atomicAdd(done, 1);
    }
    __syncthreads();
    if (ticket == 1023) {                      // exactly one block: all z done
        int t = threadIdx.x;
        float zz = __hip_atomic_load(&z[t], __ATOMIC_RELAXED, __HIP_MEMORY_SCOPE_AGENT);
        float val = (zz + fc1b[t]) * fc2W[t];
        #pragma unroll
        for (int m = 1; m < 64; m <<= 1) val += __shfl_xor(val, m);
        __syncthreads();                       // red[] reuse barrier
        if ((t & 63) == 0) red[t >> 6] = val;
        __syncthreads();
        if (t == 0) out[0] = red[0] + red[1] + red[2] + red[3] + fc2b[0];
    }
}

extern "C" void kernel_launch(void* const* d_in, const int* in_sizes, int n_in,
                              void* d_out, int out_size, void* d_ws, size_t ws_size,
                              hipStream_t stream) {
    const float* x    = (const float*)d_in[0];
    const int*   ei   = (const int*)d_in[1];   // jax x64 disabled -> int32
    const float* W1l  = (const float*)d_in[2];
    const float* b1l  = (const float*)d_in[3];
    const float* W1r  = (const float*)d_in[4];
    const float* W2l  = (const float*)d_in[5];
    const float* b2l  = (const float*)d_in[6];
    const float* W2r  = (const float*)d_in[7];
    const float* fc1W = (const float*)d_in[8];
    const float* fc1b = (const float*)d_in[9];
    const float* fc2W = (const float*)d_in[10];
    const float* fc2b = (const float*)d_in[11];
    float* out = (float*)d_out;

    // workspace layout (bytes)
    char*   ws      = (char*)d_ws;
    int*    gcnt4   = (int*)   (ws + 0);           //   800,000 B (line-padded counters)
    float*  z       = (float*) (ws + 800256);      //     1,024 B
    int*    done    = (int*)   (ws + 801280);      //       512 B
    __half* xh      = (__half*)(ws + 801792);      // 6,400,000 B
    int*    gbucket = (int*)   (ws + 7201792);     // 6,400,000 B
    float*  agg     = (float*) (ws + 13601792);    // 12,800,000 B
    float*  s       = (float*) (ws + 26401792);    //   200,000 B
    float*  t       = (float*) (ws + 26601792);    //   200,000 B
    float*  v       = (float*) (ws + 26801792);    //   200,000 B  (end 27,001,792)

    k0_half_init<<<3125,     256, 0, stream>>>(x, xh, gcnt4, z, done);
    k1_bucket   <<<K1_BLOCKS,256, 0, stream>>>(ei, gcnt4, gbucket);
    k2_agg      <<<N_GROUPS, 256, 0, stream>>>(xh, gcnt4, gbucket, agg);
    k3_mm_mfma  <<<782,      256, 0, stream>>>(x, agg, W1l, b1l, W1r, W2l, W2r, s, t);
    k4_layer2   <<<N_GROUPS,  64, 0, stream>>>(s, t, gcnt4, gbucket, b2l, v);
    k5_fc1_head <<<1024,     256, 0, stream>>>(fc1W, v, z, done, fc1b, fc2W, fc2b, out);
}